// Round 1
// baseline (87.755 us; speedup 1.0000x reference)
//
#include <hip/hip_runtime.h>
#include <hip/hip_bf16.h>

#define SS 32
#define EE 64
#define DD 256
#define LL 5

typedef unsigned int uint32;
typedef unsigned short ushort16;

static __device__ __forceinline__ ushort f2bf(float f) {
    uint32 u = __float_as_uint(f);
    uint32 r = (u + 0x7FFFu + ((u >> 16) & 1u)) >> 16;   // RNE
    return (ushort)r;
}
static __device__ __forceinline__ float bf2f(ushort h) {
    return __uint_as_float(((uint32)h) << 16);
}

// ---------------- K0: tiny setup -------------------------------------------
__global__ __launch_bounds__(256) void k0_setup(
    const float* __restrict__ sup_entities,  // (L,5,2D)
    const float* __restrict__ sup_context,   // (L,5,D)
    const int*   __restrict__ counts,        // (L,)
    float* __restrict__ ws) {
    float* ctx_center = ws;          // [L][D]
    float* cc2  = ws + 1280;         // [5]
    float* cvec = ws + 1285;         // [5]
    float* pa   = ws + 1290;         // [L][D]
    float* pb   = ws + 2570;         // [L][D]
    float* pa2  = ws + 3850;         // [5]
    float* pb2  = ws + 3855;         // [5]
    int t = threadIdx.x;
    for (int i = t; i < LL * DD; i += 256) {
        int k = i / DD, d = i - k * DD;
        float s = 0.f;
        for (int j = 0; j < 5; j++) s += sup_context[(k * 5 + j) * DD + d];
        ctx_center[i] = s * 0.2f;
    }
    for (int i = t; i < LL * 2 * DD; i += 256) {
        int k = i / (2 * DD), d = i - k * (2 * DD);
        float s = 0.f;
        for (int j = 0; j < 5; j++) s += sup_entities[(k * 5 + j) * (2 * DD) + d];
        float m = s * 0.2f;
        if (d < DD) pa[k * DD + d] = m;
        else        pb[k * DD + (d - DD)] = m;
    }
    __syncthreads();
    if (t < LL) {
        float s = 0.f;
        for (int d = 0; d < DD; d++) { float v = ctx_center[t * DD + d]; s += v * v; }
        cc2[t] = s;
        s = 0.f;
        for (int d = 0; d < DD; d++) { float v = pa[t * DD + d]; s += v * v; }
        pa2[t] = s;
        s = 0.f;
        for (int d = 0; d < DD; d++) { float v = pb[t * DD + d]; s += v * v; }
        pb2[t] = s;
    }
    if (t == 0) {
        float cnt[LL]; float total = 0.f;
        for (int k = 0; k < LL; k++) { cnt[k] = (float)counts[k] + 1.0f; total += cnt[k]; }
        for (int k = 0; k < LL; k++) cvec[k] = cnt[k] / (total - cnt[k]);
    }
}

// ---------------- K1: xW (bf16) and xself (f32) ----------------------------
// grid 256 blocks, 256 threads. 8 rows/block. K split across 4 waves,
// x broadcast via v_readlane, cross-wave reduction through LDS.
__global__ __launch_bounds__(256) void k1_gemm(
    const float* __restrict__ x, const float* __restrict__ W,
    const float* __restrict__ Wself,
    float* __restrict__ xself, ushort* __restrict__ xw) {
    int row0 = blockIdx.x * 8;
    int t = threadIdx.x, lane = t & 63, wv = t >> 6;

    float xreg[8];
    const float* xbase = x + row0 * DD + wv * 64 + lane;
#pragma unroll
    for (int r = 0; r < 8; r++) xreg[r] = xbase[r * DD];

    float4 accW[8], accS[8];
#pragma unroll
    for (int r = 0; r < 8; r++) {
        accW[r] = make_float4(0.f, 0.f, 0.f, 0.f);
        accS[r] = make_float4(0.f, 0.f, 0.f, 0.f);
    }
    const float4* Wp  = ((const float4*)W) + lane;
    const float4* Wsp = ((const float4*)Wself) + lane;
#pragma unroll 2
    for (int i = 0; i < 64; i++) {
        int kk = wv * 64 + i;
        float4 w4  = Wp[kk * 64];
        float4 ws4 = Wsp[kk * 64];
#pragma unroll
        for (int r = 0; r < 8; r++) {
            float xs = __uint_as_float(
                (uint32)__builtin_amdgcn_readlane((int)__float_as_uint(xreg[r]), i));
            accW[r].x = fmaf(xs, w4.x, accW[r].x);
            accW[r].y = fmaf(xs, w4.y, accW[r].y);
            accW[r].z = fmaf(xs, w4.z, accW[r].z);
            accW[r].w = fmaf(xs, w4.w, accW[r].w);
            accS[r].x = fmaf(xs, ws4.x, accS[r].x);
            accS[r].y = fmaf(xs, ws4.y, accS[r].y);
            accS[r].z = fmaf(xs, ws4.z, accS[r].z);
            accS[r].w = fmaf(xs, ws4.w, accS[r].w);
        }
    }
    __shared__ float4 redbuf[4][8][64];   // 32 KB
    // ---- xself ----
#pragma unroll
    for (int r = 0; r < 8; r++) redbuf[wv][r][lane] = accS[r];
    __syncthreads();
    {
        int r = t >> 5;
#pragma unroll
        for (int f = 0; f < 2; f++) {
            int l4 = (t & 31) + 32 * f;
            float4 a = redbuf[0][r][l4], b = redbuf[1][r][l4];
            float4 c = redbuf[2][r][l4], d = redbuf[3][r][l4];
            float4 s4 = make_float4(a.x + b.x + c.x + d.x, a.y + b.y + c.y + d.y,
                                    a.z + b.z + c.z + d.z, a.w + b.w + c.w + d.w);
            *(float4*)&xself[(row0 + r) * DD + l4 * 4] = s4;
        }
    }
    __syncthreads();
    // ---- xW (bf16) ----
#pragma unroll
    for (int r = 0; r < 8; r++) redbuf[wv][r][lane] = accW[r];
    __syncthreads();
    {
        int r = t >> 5;
#pragma unroll
        for (int f = 0; f < 2; f++) {
            int l4 = (t & 31) + 32 * f;
            float4 a = redbuf[0][r][l4], b = redbuf[1][r][l4];
            float4 c = redbuf[2][r][l4], d = redbuf[3][r][l4];
            float4 s4 = make_float4(a.x + b.x + c.x + d.x, a.y + b.y + c.y + d.y,
                                    a.z + b.z + c.z + d.z, a.w + b.w + c.w + d.w);
            ushort4 h;
            h.x = f2bf(s4.x); h.y = f2bf(s4.y); h.z = f2bf(s4.z); h.w = f2bf(s4.w);
            *(ushort4*)&xw[(row0 + r) * DD + l4 * 4] = h;
        }
    }
}

// ---------------- K2: context distances -> w  (128 MiB stream) -------------
// grid 2048 = (s,u) blocks, 256 threads. 16-lane groups, 4 v-rows per wave
// per pass. Output layout w[s][k][u][v].
__global__ __launch_bounds__(256) void k2_w(
    const float* __restrict__ context,
    const float* __restrict__ ctx_center,
    const float* __restrict__ cc2,
    float* __restrict__ w_out) {
    int bs = blockIdx.x;
    int s = bs >> 6, u = bs & 63;
    int t = threadIdx.x, lane = t & 63, wv = t >> 6;
    int g = lane >> 4, gl = lane & 15;

    float4 cc[5][4];
#pragma unroll
    for (int k = 0; k < 5; k++)
#pragma unroll
        for (int j = 0; j < 4; j++)
            cc[k][j] = *(const float4*)&ctx_center[k * DD + j * 64 + gl * 4];
    float cc2r[5];
#pragma unroll
    for (int k = 0; k < 5; k++) cc2r[k] = cc2[k];

    __shared__ float wbuf[5][64];
    const float* base = context + ((size_t)(s * 64 + u)) * 64 * DD;

    for (int pass = 0; pass < 4; pass++) {
        int v = pass * 16 + wv * 4 + g;
        const float* row = base + v * DD;
        float cn2 = 0.f;
        float cr[5] = {0.f, 0.f, 0.f, 0.f, 0.f};
#pragma unroll
        for (int j = 0; j < 4; j++) {
            float4 c4 = *(const float4*)&row[j * 64 + gl * 4];
            cn2 = fmaf(c4.x, c4.x, fmaf(c4.y, c4.y, fmaf(c4.z, c4.z, fmaf(c4.w, c4.w, cn2))));
#pragma unroll
            for (int k = 0; k < 5; k++) {
                float4 p = cc[k][j];
                cr[k] = fmaf(c4.x, p.x, fmaf(c4.y, p.y, fmaf(c4.z, p.z, fmaf(c4.w, p.w, cr[k]))));
            }
        }
#pragma unroll
        for (int off = 1; off < 16; off <<= 1) {
            cn2 += __shfl_xor(cn2, off);
#pragma unroll
            for (int k = 0; k < 5; k++) cr[k] += __shfl_xor(cr[k], off);
        }
        if (gl == 0) {
#pragma unroll
            for (int k = 0; k < 5; k++) {
                float d2 = cn2 - 2.f * cr[k] + cc2r[k];
                wbuf[k][v] = (u == v) ? 0.f : 1.f / fmaxf(d2, 1e-8f);
            }
        }
    }
    __syncthreads();
    for (int i = t; i < 320; i += 256) {
        int k = i >> 6, v = i & 63;
        w_out[((s * 5 + k) * 64 + u) * 64 + v] = wbuf[k][v];
    }
}

// ---------------- K3: out = xself + w.xW, fused with distance dots ---------
// grid 320 = (s, k, vhalf), 256 threads. LDS: xW slab (bf16, reused as out
// buffer) + w tile. Emits da/db only (out never hits HBM).
__global__ __launch_bounds__(256) void k3_outdots(
    const ushort* __restrict__ xw, const float* __restrict__ xself,
    const float* __restrict__ w_t,
    const float* __restrict__ pa, const float* __restrict__ pb,
    const float* __restrict__ pa2, const float* __restrict__ pb2,
    float* __restrict__ da, float* __restrict__ db) {
    int bx = blockIdx.x;
    int s = bx / 10; int rem = bx - s * 10;
    int k = rem >> 1; int v0 = (rem & 1) * 32;
    int t = threadIdx.x, lane = t & 63, wv = t >> 6;

    __shared__ ushort xw_l[64][256];   // 32 KB, reused as outb later
    __shared__ float  wt_l[64][32];    // 8 KB
    float* outb = (float*)&xw_l[0][0]; // 32 rows x 256 f32 = 32 KB

    {   // load xW slab (contiguous 32 KB)
        const uint4* src = (const uint4*)(xw + (size_t)s * EE * DD);
        uint4* dst = (uint4*)&xw_l[0][0];
#pragma unroll
        for (int j = 0; j < 8; j++) dst[j * 256 + t] = src[j * 256 + t];
    }
    {   // load w tile [u][v-local]
        const float* wsrc = w_t + ((size_t)(s * 5 + k) * 64) * 64 + v0;
        int u = t >> 3, f = t & 7;
#pragma unroll
        for (int rep = 0; rep < 2; rep++, u += 32)
            *(float4*)&wt_l[u][f * 4] = *(const float4*)&wsrc[u * 64 + f * 4];
    }
    __syncthreads();

    float4 acc[8];
    int vbase = v0 + wv * 8;
#pragma unroll
    for (int vi = 0; vi < 8; vi++)
        acc[vi] = *(const float4*)&xself[((size_t)(s * 64) + vbase + vi) * DD + lane * 4];

#pragma unroll 2
    for (int u = 0; u < 64; u++) {
        ushort4 h = *(const ushort4*)&xw_l[u][lane * 4];
        float4 xv = make_float4(bf2f(h.x), bf2f(h.y), bf2f(h.z), bf2f(h.w));
        float4 wA = *(const float4*)&wt_l[u][wv * 8];
        float4 wB = *(const float4*)&wt_l[u][wv * 8 + 4];
        float wr[8] = {wA.x, wA.y, wA.z, wA.w, wB.x, wB.y, wB.z, wB.w};
#pragma unroll
        for (int vi = 0; vi < 8; vi++) {
            acc[vi].x = fmaf(wr[vi], xv.x, acc[vi].x);
            acc[vi].y = fmaf(wr[vi], xv.y, acc[vi].y);
            acc[vi].z = fmaf(wr[vi], xv.z, acc[vi].z);
            acc[vi].w = fmaf(wr[vi], xv.w, acc[vi].w);
        }
    }
    __syncthreads();   // everyone done reading xw_l
#pragma unroll
    for (int vi = 0; vi < 8; vi++)
        *(float4*)&outb[(wv * 8 + vi) * 256 + lane * 4] = acc[vi];
    __syncthreads();

    // dot phase: 16 lanes per row, 16 d per lane
    int g = lane >> 4, gl = lane & 15;
    float4 par[5][4], pbr[5][4];
#pragma unroll
    for (int n = 0; n < 5; n++)
#pragma unroll
        for (int j = 0; j < 4; j++) {
            par[n][j] = *(const float4*)&pa[n * DD + gl * 16 + j * 4];
            pbr[n][j] = *(const float4*)&pb[n * DD + gl * 16 + j * 4];
        }
    float pa2r[5], pb2r[5];
#pragma unroll
    for (int n = 0; n < 5; n++) { pa2r[n] = pa2[n]; pb2r[n] = pb2[n]; }

    for (int pass = 0; pass < 2; pass++) {
        int lv = wv * 8 + pass * 4 + g;
        float o2 = 0.f;
        float dpa[5] = {0.f, 0.f, 0.f, 0.f, 0.f};
        float dpb[5] = {0.f, 0.f, 0.f, 0.f, 0.f};
#pragma unroll
        for (int j = 0; j < 4; j++) {
            float4 o = *(const float4*)&outb[lv * 256 + gl * 16 + j * 4];
            o2 = fmaf(o.x, o.x, fmaf(o.y, o.y, fmaf(o.z, o.z, fmaf(o.w, o.w, o2))));
#pragma unroll
            for (int n = 0; n < 5; n++) {
                float4 p = par[n][j];
                dpa[n] = fmaf(o.x, p.x, fmaf(o.y, p.y, fmaf(o.z, p.z, fmaf(o.w, p.w, dpa[n]))));
                float4 q = pbr[n][j];
                dpb[n] = fmaf(o.x, q.x, fmaf(o.y, q.y, fmaf(o.z, q.z, fmaf(o.w, q.w, dpb[n]))));
            }
        }
#pragma unroll
        for (int off = 1; off < 16; off <<= 1) {
            o2 += __shfl_xor(o2, off);
#pragma unroll
            for (int n = 0; n < 5; n++) {
                dpa[n] += __shfl_xor(dpa[n], off);
                dpb[n] += __shfl_xor(dpb[n], off);
            }
        }
        if (gl == 0) {
            int v = v0 + lv;
            int idx = ((s * 5 + k) * 64 + v) * 5;
#pragma unroll
            for (int n = 0; n < 5; n++) {
                da[idx + n] = o2 - 2.f * dpa[n] + pa2r[n];
                db[idx + n] = o2 - 2.f * dpb[n] + pb2r[n];
            }
        }
    }
}

// ---------------- K4: logits + softmax + transposed store ------------------
// grid 2048 = (s,v1), 320 threads = (v2,k). 13.1 MB write.
__global__ __launch_bounds__(320) void k4_softmax(
    const float* __restrict__ da, const float* __restrict__ db,
    const float* __restrict__ cvec, float* __restrict__ out) {
    int bx = blockIdx.x;
    int s = bx >> 6;     // v1 = bx & 63
    int t = threadIdx.x;
    int v2 = t / 5, k = t - v2 * 5;
    int v1 = bx & 63;

    const float* dap = da + ((size_t)(s * 5 + k) * 64 + v1) * 5;
    const float* dbp = db + ((size_t)(s * 5 + k) * 64 + v2) * 5;

    float l[5], m = -3.4e38f;
#pragma unroll
    for (int n = 0; n < 5; n++) {
        l[n] = dap[n] + dbp[n] + cvec[n];
        m = fmaxf(m, l[n]);
    }
    float e[5], sum = 0.f;
#pragma unroll
    for (int n = 0; n < 5; n++) { e[n] = __expf(l[n] - m); sum += e[n]; }
    float r = 1.f / sum;
    float* op = out + ((size_t)bx * 64 + v2) * 25 + k * 5;
#pragma unroll
    for (int n = 0; n < 5; n++) op[n] = e[n] * r;
}

// ---------------- launch ----------------------------------------------------
extern "C" void kernel_launch(void* const* d_in, const int* in_sizes, int n_in,
                              void* d_out, int out_size, void* d_ws, size_t ws_size,
                              hipStream_t stream) {
    const float* sup_entities = (const float*)d_in[0];
    const float* sup_context  = (const float*)d_in[1];
    const float* x            = (const float*)d_in[2];
    const float* context      = (const float*)d_in[3];
    const float* W            = (const float*)d_in[4];
    const float* Wself        = (const float*)d_in[5];
    const int*   counts       = (const int*)d_in[6];
    float* out = (float*)d_out;

    float* ws = (float*)d_ws;
    float* ctx_center = ws;                 // 1280
    float* cc2  = ws + 1280;
    float* cvec = ws + 1285;
    float* pa   = ws + 1290;
    float* pb   = ws + 2570;
    float* pa2  = ws + 3850;
    float* pb2  = ws + 3855;
    float* xself = ws + 4096;               // 524288 f32
    ushort* xw   = (ushort*)(ws + 528384);  // 524288 bf16
    float* wt    = ws + 790528;             // 655360 f32
    float* da    = ws + 1445888;            // 51200
    float* db    = ws + 1497088;            // 51200

    k0_setup<<<1, 256, 0, stream>>>(sup_entities, sup_context, counts, ws);
    k1_gemm<<<256, 256, 0, stream>>>(x, W, Wself, xself, xw);
    k2_w<<<SS * EE, 256, 0, stream>>>(context, ctx_center, cc2, wt);
    k3_outdots<<<320, 256, 0, stream>>>(xw, xself, wt, pa, pb, pa2, pb2, da, db);
    k4_softmax<<<SS * EE, 320, 0, stream>>>(da, db, cvec, out);
}

// Round 2
// 61.572 us; speedup vs baseline: 1.4252x; 1.4252x over previous
//
#include <hip/hip_runtime.h>
#include <hip/hip_bf16.h>

#define SS 32
#define EE 64
#define DD 256
#define LL 5

typedef unsigned int uint32;

static __device__ __forceinline__ ushort f2bf(float f) {
    uint32 u = __float_as_uint(f);
    uint32 r = (u + 0x7FFFu + ((u >> 16) & 1u)) >> 16;   // RNE
    return (ushort)r;
}
static __device__ __forceinline__ float bf2f(ushort h) {
    return __uint_as_float(((uint32)h) << 16);
}

// ws layout (f32 units):
//   pa   = ws + 0      (1280)   pb  = ws + 1280 (1280)
//   pa2  = ws + 2560   (5)      pb2 = ws + 2565 (5)    cvec = ws + 2570 (5)
//   xself= ws + 4096   (524288)
//   xw   = (ushort*)(ws + 528384)  (524288 bf16)
//   wt   = ws + 790528 (655360)  [s][k][u][v]
//   da   = ws + 1445888 (51200)  db = ws + 1497088 (51200)

// ================= K_A: GEMM + context-distance stream + setup =============
// blocks 0..255   : GEMM  x@W (bf16 out) and x@Wself (f32 out), 8 rows each
// blocks 256..2303: per-(s,u) context slab -> w weights
// block  2304     : proto means / norms / cvec
__global__ __launch_bounds__(256) void kA(
    const float* __restrict__ sup_entities, const float* __restrict__ sup_context,
    const float* __restrict__ x, const float* __restrict__ context,
    const float* __restrict__ W, const float* __restrict__ Wself,
    const int* __restrict__ counts, float* __restrict__ ws) {

    __shared__ float smem[8192];   // 32 KB, repurposed per branch
    int bx = blockIdx.x;
    int t = threadIdx.x, lane = t & 63, wv = t >> 6;

    float* xself = ws + 4096;
    ushort* xw = (ushort*)(ws + 528384);
    float* wt = ws + 790528;

    if (bx < 256) {
        // ---------------- GEMM branch ----------------
        int row0 = bx * 8;
        float xreg[8];
        const float* xbase = x + row0 * DD + wv * 64 + lane;
#pragma unroll
        for (int r = 0; r < 8; r++) xreg[r] = xbase[r * DD];

        float4 accW[8], accS[8];
#pragma unroll
        for (int r = 0; r < 8; r++) {
            accW[r] = make_float4(0.f, 0.f, 0.f, 0.f);
            accS[r] = make_float4(0.f, 0.f, 0.f, 0.f);
        }
        const float4* Wp  = ((const float4*)W) + lane;
        const float4* Wsp = ((const float4*)Wself) + lane;
#pragma unroll 2
        for (int i = 0; i < 64; i++) {
            int kk = wv * 64 + i;
            float4 w4  = Wp[kk * 64];
            float4 ws4 = Wsp[kk * 64];
#pragma unroll
            for (int r = 0; r < 8; r++) {
                float xs = __uint_as_float(
                    (uint32)__builtin_amdgcn_readlane((int)__float_as_uint(xreg[r]), i));
                accW[r].x = fmaf(xs, w4.x, accW[r].x);
                accW[r].y = fmaf(xs, w4.y, accW[r].y);
                accW[r].z = fmaf(xs, w4.z, accW[r].z);
                accW[r].w = fmaf(xs, w4.w, accW[r].w);
                accS[r].x = fmaf(xs, ws4.x, accS[r].x);
                accS[r].y = fmaf(xs, ws4.y, accS[r].y);
                accS[r].z = fmaf(xs, ws4.z, accS[r].z);
                accS[r].w = fmaf(xs, ws4.w, accS[r].w);
            }
        }
        float4* redbuf = (float4*)smem;   // [4][8][64]
#pragma unroll
        for (int r = 0; r < 8; r++) redbuf[(wv * 8 + r) * 64 + lane] = accS[r];
        __syncthreads();
        {
            int r = t >> 5;
#pragma unroll
            for (int f = 0; f < 2; f++) {
                int l4 = (t & 31) + 32 * f;
                float4 a = redbuf[(0 * 8 + r) * 64 + l4], b = redbuf[(1 * 8 + r) * 64 + l4];
                float4 c = redbuf[(2 * 8 + r) * 64 + l4], d = redbuf[(3 * 8 + r) * 64 + l4];
                float4 s4 = make_float4(a.x + b.x + c.x + d.x, a.y + b.y + c.y + d.y,
                                        a.z + b.z + c.z + d.z, a.w + b.w + c.w + d.w);
                *(float4*)&xself[(row0 + r) * DD + l4 * 4] = s4;
            }
        }
        __syncthreads();
#pragma unroll
        for (int r = 0; r < 8; r++) redbuf[(wv * 8 + r) * 64 + lane] = accW[r];
        __syncthreads();
        {
            int r = t >> 5;
#pragma unroll
            for (int f = 0; f < 2; f++) {
                int l4 = (t & 31) + 32 * f;
                float4 a = redbuf[(0 * 8 + r) * 64 + l4], b = redbuf[(1 * 8 + r) * 64 + l4];
                float4 c = redbuf[(2 * 8 + r) * 64 + l4], d = redbuf[(3 * 8 + r) * 64 + l4];
                float4 s4 = make_float4(a.x + b.x + c.x + d.x, a.y + b.y + c.y + d.y,
                                        a.z + b.z + c.z + d.z, a.w + b.w + c.w + d.w);
                ushort4 h;
                h.x = f2bf(s4.x); h.y = f2bf(s4.y); h.z = f2bf(s4.z); h.w = f2bf(s4.w);
                *(ushort4*)&xw[(row0 + r) * DD + l4 * 4] = h;
            }
        }
    } else if (bx < 2304) {
        // ---------------- context stream branch ----------------
        int bs = bx - 256;
        int s = bs >> 6, u = bs & 63;
        float* cc_l  = smem;          // [5][256]
        float* cc2_l = smem + 1280;   // [5]
        float* wbuf  = smem + 1288;   // [5][64]

        for (int i = t; i < 1280; i += 256) {
            int k = i >> 8, d = i & 255;
            float sum = 0.f;
#pragma unroll
            for (int j = 0; j < 5; j++) sum += sup_context[(k * 5 + j) * DD + d];
            cc_l[i] = sum * 0.2f;
        }
        __syncthreads();
        if (t < 80) {
            int k = t >> 4, gl = t & 15;
            float p = 0.f;
#pragma unroll
            for (int j = 0; j < 16; j++) { float v = cc_l[k * 256 + gl * 16 + j]; p = fmaf(v, v, p); }
#pragma unroll
            for (int off = 1; off < 16; off <<= 1) p += __shfl_xor(p, off);
            if (gl == 0) cc2_l[k] = p;
        }
        __syncthreads();

        int g = lane >> 4, gl = lane & 15;
        const float* base = context + ((size_t)bs) * (EE * DD);
        for (int pass = 0; pass < 4; pass++) {
            int v = pass * 16 + wv * 4 + g;
            const float* row = base + v * DD;
            float cn2 = 0.f;
            float cr[5] = {0.f, 0.f, 0.f, 0.f, 0.f};
#pragma unroll
            for (int j = 0; j < 4; j++) {
                float4 c4 = *(const float4*)&row[j * 64 + gl * 4];
                cn2 = fmaf(c4.x, c4.x, fmaf(c4.y, c4.y, fmaf(c4.z, c4.z, fmaf(c4.w, c4.w, cn2))));
#pragma unroll
                for (int k = 0; k < 5; k++) {
                    float4 p = *(const float4*)&cc_l[k * 256 + j * 64 + gl * 4];
                    cr[k] = fmaf(c4.x, p.x, fmaf(c4.y, p.y, fmaf(c4.z, p.z, fmaf(c4.w, p.w, cr[k]))));
                }
            }
#pragma unroll
            for (int off = 1; off < 16; off <<= 1) {
                cn2 += __shfl_xor(cn2, off);
#pragma unroll
                for (int k = 0; k < 5; k++) cr[k] += __shfl_xor(cr[k], off);
            }
            if (gl == 0) {
#pragma unroll
                for (int k = 0; k < 5; k++) {
                    float d2 = cn2 - 2.f * cr[k] + cc2_l[k];
                    wbuf[k * 64 + v] = (u == v) ? 0.f : 1.f / fmaxf(d2, 1e-8f);
                }
            }
        }
        __syncthreads();
        for (int i = t; i < 320; i += 256) {
            int k = i >> 6, v = i & 63;
            wt[(((size_t)s * 5 + k) * 64 + u) * 64 + v] = wbuf[k * 64 + v];
        }
    } else {
        // ---------------- setup branch ----------------
        for (int i = t; i < 2560; i += 256) {
            int k = i >> 9, d = i & 511;
            float s = 0.f;
#pragma unroll
            for (int j = 0; j < 5; j++) s += sup_entities[(k * 5 + j) * 512 + d];
            float m = s * 0.2f;
            if (d < 256) ws[k * 256 + d] = m;
            else         ws[1280 + k * 256 + (d - 256)] = m;
        }
        __syncthreads();
        if (t < 10) {
            const float* p = ws + ((t >= 5) ? 1280 : 0) + (t % 5) * 256;
            float s = 0.f;
            for (int d = 0; d < 256; d++) s = fmaf(p[d], p[d], s);
            ws[2560 + t] = s;   // pa2[0..5), pb2[5..10)
        }
        if (t == 0) {
            float cnt[5], tot = 0.f;
#pragma unroll
            for (int k = 0; k < 5; k++) { cnt[k] = (float)counts[k] + 1.0f; tot += cnt[k]; }
#pragma unroll
            for (int k = 0; k < 5; k++) ws[2570 + k] = cnt[k] / (tot - cnt[k]);
        }
    }
}

// ================= K_B: out = xself + w.xW  fused with distance dots =======
// 256 blocks = (s, vgroup of 8 v). 4 waves: wave handles 2 v x 5 k.
__global__ __launch_bounds__(256) void kB(const float* __restrict__ ws) {
    const ushort* xw = (const ushort*)(ws + 528384);
    const float* xself = ws + 4096;
    const float* wt = ws + 790528;
    float* da = (float*)(ws + 1445888);
    float* db = (float*)(ws + 1497088);

    int bx = blockIdx.x;
    int s = bx >> 3, vg = bx & 7;
    int t = threadIdx.x, lane = t & 63, wv = t >> 6;

    __shared__ ushort xw_l[64][256];   // 32 KB
    __shared__ float  w_l[5][64][8];   // 10 KB

    {
        const uint4* src = (const uint4*)(xw + (size_t)s * (EE * DD));
        uint4* dst = (uint4*)&xw_l[0][0];
#pragma unroll
        for (int j = 0; j < 8; j++) dst[j * 256 + t] = src[j * 256 + t];
    }
    for (int i = t; i < 640; i += 256) {
        int k = i >> 7; int r = i & 127; int u = r >> 1; int h = r & 1;
        *(float4*)&w_l[k][u][h * 4] =
            *(const float4*)&wt[(((size_t)s * 5 + k) * 64 + u) * 64 + vg * 8 + h * 4];
    }
    __syncthreads();

    int vb = wv * 2;
    float4 acc[2][5];
#pragma unroll
    for (int vi = 0; vi < 2; vi++) {
        float4 xs = *(const float4*)&xself[((size_t)s * 64 + vg * 8 + vb + vi) * DD + lane * 4];
#pragma unroll
        for (int k = 0; k < 5; k++) acc[vi][k] = xs;
    }

#pragma unroll 4
    for (int u = 0; u < 64; u++) {
        ushort4 h4 = *(const ushort4*)&xw_l[u][lane * 4];
        float4 xv = make_float4(bf2f(h4.x), bf2f(h4.y), bf2f(h4.z), bf2f(h4.w));
#pragma unroll
        for (int k = 0; k < 5; k++) {
            float2 w2 = *(const float2*)&w_l[k][u][vb];
            acc[0][k].x = fmaf(w2.x, xv.x, acc[0][k].x);
            acc[0][k].y = fmaf(w2.x, xv.y, acc[0][k].y);
            acc[0][k].z = fmaf(w2.x, xv.z, acc[0][k].z);
            acc[0][k].w = fmaf(w2.x, xv.w, acc[0][k].w);
            acc[1][k].x = fmaf(w2.y, xv.x, acc[1][k].x);
            acc[1][k].y = fmaf(w2.y, xv.y, acc[1][k].y);
            acc[1][k].z = fmaf(w2.y, xv.z, acc[1][k].z);
            acc[1][k].w = fmaf(w2.y, xv.w, acc[1][k].w);
        }
    }

    // epilogue: 11 dot-reductions per (v,k)
    float4 pA[5], pB[5];
#pragma unroll
    for (int n = 0; n < 5; n++) {
        pA[n] = *(const float4*)&ws[n * 256 + lane * 4];
        pB[n] = *(const float4*)&ws[1280 + n * 256 + lane * 4];
    }
    float pa2r[5], pb2r[5];
#pragma unroll
    for (int n = 0; n < 5; n++) { pa2r[n] = ws[2560 + n]; pb2r[n] = ws[2565 + n]; }

#pragma unroll
    for (int vi = 0; vi < 2; vi++) {
#pragma unroll
        for (int k = 0; k < 5; k++) {
            float4 o = acc[vi][k];
            float r[11];
            r[0] = fmaf(o.x, o.x, fmaf(o.y, o.y, fmaf(o.z, o.z, o.w * o.w)));
#pragma unroll
            for (int n = 0; n < 5; n++) {
                float4 p = pA[n];
                r[1 + n] = fmaf(o.x, p.x, fmaf(o.y, p.y, fmaf(o.z, p.z, o.w * p.w)));
                float4 q = pB[n];
                r[6 + n] = fmaf(o.x, q.x, fmaf(o.y, q.y, fmaf(o.z, q.z, o.w * q.w)));
            }
#pragma unroll
            for (int off = 1; off < 64; off <<= 1) {
#pragma unroll
                for (int q = 0; q < 11; q++) r[q] += __shfl_xor(r[q], off);
            }
            if (lane == 0) {
                int v = vg * 8 + vb + vi;
                size_t idx = (((size_t)s * 5 + k) * 64 + v) * 5;
#pragma unroll
                for (int n = 0; n < 5; n++) {
                    da[idx + n] = r[0] - 2.f * r[1 + n] + pa2r[n];
                    db[idx + n] = r[0] - 2.f * r[6 + n] + pb2r[n];
                }
            }
        }
    }
}

// ================= K_C: logits + softmax + coalesced store ==================
__global__ __launch_bounds__(320) void kC(const float* __restrict__ ws,
                                          float* __restrict__ out) {
    const float* da = ws + 1445888;
    const float* db = ws + 1497088;
    int bx = blockIdx.x;
    int s = bx >> 6, v1 = bx & 63;
    int t = threadIdx.x;
    int v2 = t / 5, k = t - v2 * 5;

    __shared__ float ob[1600];
    __shared__ float cvs[5];
    if (t < 5) cvs[t] = ws[2570 + t];

    const float* dap = da + (((size_t)s * 5 + k) * 64 + v1) * 5;
    const float* dbp = db + (((size_t)s * 5 + k) * 64 + v2) * 5;
    float l0[5];
#pragma unroll
    for (int n = 0; n < 5; n++) l0[n] = dap[n] + dbp[n];
    __syncthreads();
    float m = -3.4e38f;
#pragma unroll
    for (int n = 0; n < 5; n++) { l0[n] += cvs[n]; m = fmaxf(m, l0[n]); }
    float e[5], sum = 0.f;
#pragma unroll
    for (int n = 0; n < 5; n++) { e[n] = __expf(l0[n] - m); sum += e[n]; }
    float r = 1.f / sum;
#pragma unroll
    for (int n = 0; n < 5; n++) ob[t * 5 + n] = e[n] * r;
    __syncthreads();

    const float4* ob4 = (const float4*)ob;
    float4* op = (float4*)(out + (size_t)bx * 1600);
    for (int i = t; i < 400; i += 320) op[i] = ob4[i];
}

// ---------------- launch ----------------------------------------------------
extern "C" void kernel_launch(void* const* d_in, const int* in_sizes, int n_in,
                              void* d_out, int out_size, void* d_ws, size_t ws_size,
                              hipStream_t stream) {
    const float* sup_entities = (const float*)d_in[0];
    const float* sup_context  = (const float*)d_in[1];
    const float* x            = (const float*)d_in[2];
    const float* context      = (const float*)d_in[3];
    const float* W            = (const float*)d_in[4];
    const float* Wself        = (const float*)d_in[5];
    const int*   counts       = (const int*)d_in[6];
    float* out = (float*)d_out;
    float* ws = (float*)d_ws;

    kA<<<2305, 256, 0, stream>>>(sup_entities, sup_context, x, context, W, Wself, counts, ws);
    kB<<<256, 256, 0, stream>>>(ws);
    kC<<<SS * EE, 320, 0, stream>>>(ws, out);
}